// Round 8
// baseline (1517.774 us; speedup 1.0000x reference)
//
#include <hip/hip_runtime.h>
#include <math.h>

// Problem constants (B,L,H,NH fixed by reference)
#define BB 4
#define LL 512
#define HH 512
#define NHH 8
#define DKK 64
#define RIN 53

__device__ inline void fma4(float4& a, float s, const float4& b) {
    a.x = fmaf(s, b.x, a.x); a.y = fmaf(s, b.y, a.y);
    a.z = fmaf(s, b.z, a.z); a.w = fmaf(s, b.w, a.w);
}
__device__ inline float4 add4(const float4& a, const float4& b) {
    return make_float4(a.x + b.x, a.y + b.y, a.z + b.z, a.w + b.w);
}
__device__ inline float4 shfl_xor4(const float4& v, int m) {
    return make_float4(__shfl_xor(v.x, m, 64), __shfl_xor(v.y, m, 64),
                       __shfl_xor(v.z, m, 64), __shfl_xor(v.w, m, 64));
}

// ---------------------------------------------------------------------------
// Kernel 1: fused QKV projection.
// x[B*L, H] @ {wq|wk|wv}[H,H] + bias -> q/k/v stored [B,NH,L,DK].
// ---------------------------------------------------------------------------
__global__ __launch_bounds__(256) void k_qkv(
    const float* __restrict__ x,
    const float* __restrict__ wq, const float* __restrict__ bq,
    const float* __restrict__ wk, const float* __restrict__ bk,
    const float* __restrict__ wv, const float* __restrict__ bv,
    float* __restrict__ qb, float* __restrict__ kb, float* __restrict__ vb)
{
    __shared__ float As[64][20];   // 64 rows x 16 k (pad 20 to dodge bank conflicts)
    __shared__ float Bs[16][64];

    const int t  = threadIdx.x;
    const int bm = blockIdx.x;          // 0..31
    const int bn = blockIdx.y;          // 0..23
    const int mat = bn >> 3;            // 0:q 1:k 2:v
    const float* w    = (mat == 0) ? wq : (mat == 1) ? wk : wv;
    const float* bias = (mat == 0) ? bq : (mat == 1) ? bk : bv;
    float* dst        = (mat == 0) ? qb : (mat == 1) ? kb : vb;
    const int n0 = (bn & 7) * 64;       // col base within 512

    const int tx = t & 15, ty = t >> 4;
    float acc[4][4] = {};

    const int ar = t >> 2, ak4 = t & 3;     // A staging: row, k-quad
    const int wkk = t >> 4, wn4 = t & 15;   // B staging

    for (int k0 = 0; k0 < HH; k0 += 16) {
        *(float4*)(&As[ar][ak4 * 4]) =
            *(const float4*)(x + (bm * 64 + ar) * HH + k0 + ak4 * 4);
        *(float4*)(&Bs[wkk][wn4 * 4]) =
            *(const float4*)(w + (k0 + wkk) * HH + n0 + wn4 * 4);
        __syncthreads();
#pragma unroll
        for (int kk = 0; kk < 16; ++kk) {
            const float a0 = As[ty * 4 + 0][kk];
            const float a1 = As[ty * 4 + 1][kk];
            const float a2 = As[ty * 4 + 2][kk];
            const float a3 = As[ty * 4 + 3][kk];
            const float4 b4 = *(const float4*)(&Bs[kk][tx * 4]);
            acc[0][0] = fmaf(a0, b4.x, acc[0][0]); acc[0][1] = fmaf(a0, b4.y, acc[0][1]);
            acc[0][2] = fmaf(a0, b4.z, acc[0][2]); acc[0][3] = fmaf(a0, b4.w, acc[0][3]);
            acc[1][0] = fmaf(a1, b4.x, acc[1][0]); acc[1][1] = fmaf(a1, b4.y, acc[1][1]);
            acc[1][2] = fmaf(a1, b4.z, acc[1][2]); acc[1][3] = fmaf(a1, b4.w, acc[1][3]);
            acc[2][0] = fmaf(a2, b4.x, acc[2][0]); acc[2][1] = fmaf(a2, b4.y, acc[2][1]);
            acc[2][2] = fmaf(a2, b4.z, acc[2][2]); acc[2][3] = fmaf(a2, b4.w, acc[2][3]);
            acc[3][0] = fmaf(a3, b4.x, acc[3][0]); acc[3][1] = fmaf(a3, b4.y, acc[3][1]);
            acc[3][2] = fmaf(a3, b4.z, acc[3][2]); acc[3][3] = fmaf(a3, b4.w, acc[3][3]);
        }
        __syncthreads();
    }

    // epilogue: add bias, scatter into [B,NH,L,DK]
    const int ncol = n0 + tx * 4;           // within 512; 4 cols stay in one head
    const float4 b4 = *(const float4*)(bias + ncol);
    const int h = ncol >> 6, d0 = ncol & 63;
#pragma unroll
    for (int i = 0; i < 4; ++i) {
        const int grow = bm * 64 + ty * 4 + i;     // b*L + iseq
        const int b = grow >> 9, iseq = grow & 511;
        float4 r;
        r.x = acc[i][0] + b4.x; r.y = acc[i][1] + b4.y;
        r.z = acc[i][2] + b4.z; r.w = acc[i][3] + b4.w;
        *(float4*)(dst + ((size_t)(b * NHH + h) * LL + iseq) * DKK + d0) = r;
    }
}

// ---------------------------------------------------------------------------
// Kernel 2: ref-covariate MLP (R1 fix: LDS-staged rows; see journal).
// ---------------------------------------------------------------------------
__global__ __launch_bounds__(256) void k_refmlp(
    const float* __restrict__ refCov,
    const float* __restrict__ r1w, const float* __restrict__ r1b,
    const float* __restrict__ r2w, const float* __restrict__ r2b,
    float* __restrict__ ref)
{
    __shared__ float cov[256 * RIN];   // 13568 floats = 54272 B -> 3 blocks/CU

    const int t = threadIdx.x;
    const size_t base = (size_t)blockIdx.x * (256 * RIN);

    { // coalesced staging: 3392 float4s = 13 full passes + 64-thread tail
        const float4* src = (const float4*)(refCov + base);
        float4* dst = (float4*)cov;
#pragma unroll
        for (int p = 0; p < 13; ++p) dst[p * 256 + t] = src[p * 256 + t];
        if (t < 64) dst[13 * 256 + t] = src[13 * 256 + t];
    }
    __syncthreads();

    const int pi = blockIdx.x * 256 + t;            // (b*L+i)*L + j  (< 2^20)
    const int j  = pi & 511;
    const int bi = pi >> 9;                         // b*L + i
    const int b  = bi >> 9, i = bi & 511;
    const float* cw = cov + t * RIN;

    float hid[32];
#pragma unroll
    for (int h = 0; h < 32; ++h) hid[h] = r1b[h];

#pragma unroll 4
    for (int kk = 0; kk < RIN; ++kk) {
        const float c = cw[kk];
#pragma unroll
        for (int h = 0; h < 32; ++h)
            hid[h] = fmaf(c, r1w[kk * 32 + h], hid[h]);
    }

    float out[8];
#pragma unroll
    for (int o = 0; o < 8; ++o) out[o] = r2b[o];
#pragma unroll
    for (int h = 0; h < 32; ++h) {
        const float hv = fmaxf(hid[h], 0.0f);
#pragma unroll
        for (int o = 0; o < 8; ++o)
            out[o] = fmaf(hv, r2w[h * 8 + o], out[o]);
    }
#pragma unroll
    for (int o = 0; o < 8; ++o)
        ref[((size_t)(b * NHH + o) * LL + i) * LL + j] = out[o];
}

// ---------------------------------------------------------------------------
// Kernel 3: FUSED scores+softmax+ref-softmax+combine+PV.
// R7 lesson: holding s[64]+rv[64]+acc[64] regs at once under
// __launch_bounds__(256,2)'s 256-VGPR cap forced spills -> 567us (> R4's
// split 545). R8 fix: rv arrays eliminated. Ref softmax is STREAMED:
//   pass A: online (flash-style) masked max+denominator over the refc row,
//           16-reg window per 128-chunk, running (mref,dref) with rescale,
//           then 3-step cross-lane merge over the 8 c-lanes.
//   PV pass: re-read refc chunk (issued before V-staging barrier to hide
//           latency), recompute exp(w-mref) on the fly, combine with the
//           invda-prescaled attn value, accumulate tsum inline, FMA.
// Cost: +1 refc row read (L3-resident) + 64 extra v_exp per thread.
// Benefit: peak live set ~175 VGPR -> no spill at (256,2).
// uni flag shared: attn and ref masks are identical by construction.
// ---------------------------------------------------------------------------
__global__ __launch_bounds__(256, 2) void k_attn_pv(
    const float* __restrict__ qb, const float* __restrict__ kb,
    const float* __restrict__ vb, const int* __restrict__ mask,
    const float* __restrict__ refc,
    float* __restrict__ aout)
{
    __shared__ float4 q4s[16][32];    // [d4][row]
    __shared__ float4 k4s[16][128];   // [d4][j_local]  (K, then reused for V)
    __shared__ float  mval[LL];

    const int t  = threadIdx.x;
    const int bh = blockIdx.x;        // b*NH + h
    const int b  = bh >> 3, h = bh & 7;
    const int i0 = blockIdx.y * 32;
    const int r  = t >> 3, c = t & 7;

    { // stage Q tile (32 rows x 64 d) and mask row
        const int d4 = t >> 4, r0 = t & 15;
#pragma unroll
        for (int p = 0; p < 2; ++p) {
            const int rr = r0 + p * 16;
            q4s[d4][rr] = *(const float4*)(qb + ((size_t)bh * LL + i0 + rr) * DKK + d4 * 4);
        }
#pragma unroll
        for (int p = 0; p < 2; ++p) {
            const int jj = t + p * 256;
            mval[jj] = (mask[b * LL + jj] != 0) ? 1.0f : 0.0f;
        }
    }

    float s0[16], s1[16], s2[16], s3[16];

    auto compChunk = [&](float (&SS)[16], int CH) {
        { // stage K chunk: 128 j x 16 d4
            const int d4s = t >> 4, jb0 = t & 15;
#pragma unroll
            for (int p = 0; p < 8; ++p) {
                const int jl = jb0 + p * 16;
                k4s[d4s][jl] =
                    *(const float4*)(kb + ((size_t)bh * LL + CH * 128 + jl) * DKK + d4s * 4);
            }
        }
        __syncthreads();
#pragma unroll
        for (int mm = 0; mm < 16; ++mm) SS[mm] = 0.0f;
        for (int d4 = 0; d4 < 16; ++d4) {
            const float4 qv = q4s[d4][r];
#pragma unroll
            for (int mm = 0; mm < 16; ++mm) {
                const float4 kv = k4s[d4][c + 8 * mm];
                SS[mm] = fmaf(qv.x, kv.x, SS[mm]);
                SS[mm] = fmaf(qv.y, kv.y, SS[mm]);
                SS[mm] = fmaf(qv.z, kv.z, SS[mm]);
                SS[mm] = fmaf(qv.w, kv.w, SS[mm]);
            }
        }
        __syncthreads();
    };

    compChunk(s0, 0); compChunk(s1, 1); compChunk(s2, 2); compChunk(s3, 3);

    const bool rowv = mval[i0 + r] > 0.5f;
    float mx;
    float dsum;

    auto red8max = [&](float v) {
        for (int o = 1; o < 8; o <<= 1) v = fmaxf(v, __shfl_xor(v, o, 64));
        return v;
    };
    auto red8sum = [&](float v) {
        for (int o = 1; o < 8; o <<= 1) v += __shfl_xor(v, o, 64);
        return v;
    };

    // -------- attention softmax (s arrays kept; become invda-scaled P) ----
    auto maskScale = [&](float (&SS)[16], int CH) {
#pragma unroll
        for (int mm = 0; mm < 16; ++mm) {
            const int jj = c + 8 * (CH * 16 + mm);
            const bool val = rowv && (mval[jj] > 0.5f);
            SS[mm] = val ? SS[mm] * 0.125f : -INFINITY;
            mx = fmaxf(mx, SS[mm]);
        }
    };
    mx = -INFINITY;
    maskScale(s0, 0); maskScale(s1, 1); maskScale(s2, 2); maskScale(s3, 3);
    mx = red8max(mx);
    const bool uni = (mx == -INFINITY);   // same condition for attn and ref

    auto expSum = [&](float (&SS)[16]) {
#pragma unroll
        for (int mm = 0; mm < 16; ++mm) {
            float pv;
            if (uni)                       pv = 1.0f;
            else if (SS[mm] == -INFINITY)  pv = 0.0f;
            else                           pv = __expf(SS[mm] - mx);
            SS[mm] = pv; dsum += pv;
        }
    };
    dsum = 0.0f;
    expSum(s0); expSum(s1); expSum(s2); expSum(s3);
    const float invda = 1.0f / red8sum(dsum);
    {
        auto scaleS = [&](float (&SS)[16]) {
#pragma unroll
            for (int mm = 0; mm < 16; ++mm) SS[mm] *= invda;
        };
        scaleS(s0); scaleS(s1); scaleS(s2); scaleS(s3);
    }

    // -------- ref softmax stats: online streaming pass (no rv storage) ----
    const float* rrow = refc + ((size_t)bh * LL + i0 + r) * LL;
    float mref = -INFINITY, dref = 0.0f;
#pragma unroll
    for (int CH = 0; CH < 4; ++CH) {
        float w[16];
        float lm = -INFINITY;
#pragma unroll
        for (int mm = 0; mm < 16; ++mm) {
            const int jj = c + 8 * (CH * 16 + mm);
            const bool val = rowv && (mval[jj] > 0.5f);
            w[mm] = val ? rrow[jj] : -INFINITY;
            lm = fmaxf(lm, w[mm]);
        }
        if (lm > mref) {
            dref = (mref == -INFINITY) ? 0.0f : dref * __expf(mref - lm);
            mref = lm;
        }
        if (mref != -INFINITY) {
#pragma unroll
            for (int mm = 0; mm < 16; ++mm)
                dref += (w[mm] == -INFINITY) ? 0.0f : __expf(w[mm] - mref);
        }
    }
    // cross-lane merge of (mref, dref) over the 8 c-lanes
#pragma unroll
    for (int o = 1; o < 8; o <<= 1) {
        const float mo = __shfl_xor(mref, o, 64);
        const float do_ = __shfl_xor(dref, o, 64);
        const float mn = fmaxf(mref, mo);
        if (mn == -INFINITY) {
            dref = 0.0f;
        } else {
            const float sa = (mref == -INFINITY) ? 0.0f : __expf(mref - mn);
            const float sb = (mo   == -INFINITY) ? 0.0f : __expf(mo   - mn);
            dref = dref * sa + do_ * sb;
        }
        mref = mn;
    }
    const float invdr = uni ? (1.0f / 512.0f) : (1.0f / dref);

    // -------- PV with streamed combine --------
    float4 acc[16];
#pragma unroll
    for (int d4 = 0; d4 < 16; ++d4) acc[d4] = make_float4(0.f, 0.f, 0.f, 0.f);
    float tsum = 0.0f;

    auto pvChunk = [&](float (&SS)[16], int CH) {
        // issue refc chunk loads early (independent of LDS), hide under barrier
        float w[16];
#pragma unroll
        for (int mm = 0; mm < 16; ++mm)
            w[mm] = rrow[c + 8 * (CH * 16 + mm)];
        __syncthreads();   // previous chunk's k4s reads done
        { // stage V chunk: 128 j x 16 d4 (same pattern as K)
            const int d4s = t >> 4, jb0 = t & 15;
#pragma unroll
            for (int p = 0; p < 8; ++p) {
                const int jl = jb0 + p * 16;
                k4s[d4s][jl] =
                    *(const float4*)(vb + ((size_t)bh * LL + CH * 128 + jl) * DKK + d4s * 4);
            }
        }
        __syncthreads();
#pragma unroll
        for (int mm = 0; mm < 16; ++mm) {
            const int jj = c + 8 * (CH * 16 + mm);
            const bool val = rowv && (mval[jj] > 0.5f);
            float rvp;
            if (uni)      rvp = 1.0f;
            else if (!val) rvp = 0.0f;
            else          rvp = __expf(w[mm] - mref);
            const float cm = SS[mm] + rvp * invdr;
            tsum += cm;
            const int jl = c + 8 * mm;
#pragma unroll
            for (int d4 = 0; d4 < 16; ++d4)
                fma4(acc[d4], cm, k4s[d4][jl]);
        }
    };
    pvChunk(s0, 0); pvChunk(s1, 1); pvChunk(s2, 2); pvChunk(s3, 3);

    const float invt = 1.0f / red8sum(tsum);

    // -------- reduce-scatter over the 8 c-lanes of this row ---------------
    // After step xor-m, lane keeps the half selected by its (c & m) bit;
    // final: lane c holds d4 in {2c, 2c+1} i.e. d in [8c, 8c+8).
    const bool k4lo = (c & 4) == 0;
    float4 r8[8];
#pragma unroll
    for (int i = 0; i < 8; ++i) {
        const float4 keep = k4lo ? acc[i] : acc[i + 8];
        const float4 send = k4lo ? acc[i + 8] : acc[i];
        r8[i] = add4(keep, shfl_xor4(send, 4));
    }
    const bool k2lo = (c & 2) == 0;
    float4 r4[4];
#pragma unroll
    for (int i = 0; i < 4; ++i) {
        const float4 keep = k2lo ? r8[i] : r8[i + 4];
        const float4 send = k2lo ? r8[i + 4] : r8[i];
        r4[i] = add4(keep, shfl_xor4(send, 2));
    }
    const bool k1lo = (c & 1) == 0;
    float4 r2[2];
#pragma unroll
    for (int i = 0; i < 2; ++i) {
        const float4 keep = k1lo ? r4[i] : r4[i + 2];
        const float4 send = k1lo ? r4[i + 2] : r4[i];
        r2[i] = add4(keep, shfl_xor4(send, 1));
    }
#pragma unroll
    for (int i = 0; i < 2; ++i) {
        r2[i].x *= invt; r2[i].y *= invt; r2[i].z *= invt; r2[i].w *= invt;
    }
    float* dst = aout + ((size_t)((b * LL + i0 + r) * NHH + h)) * DKK + c * 8;
    *(float4*)(dst)     = r2[0];
    *(float4*)(dst + 4) = r2[1];
}

// ---------------------------------------------------------------------------
// Kernel 4: out-projection + bias + residual + LayerNorm, fused.
// ---------------------------------------------------------------------------
__global__ __launch_bounds__(256) void k_proj_ln(
    const float* __restrict__ aout, const float* __restrict__ wo,
    const float* __restrict__ bo, const float* __restrict__ x,
    const float* __restrict__ ln_g, const float* __restrict__ ln_b,
    float* __restrict__ out)
{
    __shared__ float xs[8][20];
    __shared__ float ws[16][512];

    const int t   = threadIdx.x;
    const int m0  = blockIdx.x * 8;
    const int row = t >> 5;        // 0..7
    const int c16 = t & 31;        // col groups: col = c16*4 + q*128
    float4 acc[4] = {};

    for (int k0 = 0; k0 < HH; k0 += 16) {
        if (t < 32) {
            const int rr = t >> 2, k4 = t & 3;
            *(float4*)(&xs[rr][k4 * 4]) =
                *(const float4*)(aout + (size_t)(m0 + rr) * HH + k0 + k4 * 4);
        }
#pragma unroll
        for (int p = 0; p < 8; ++p) {
            const int flat = p * 256 + t;
            const int kk = flat >> 7, n4 = flat & 127;
            *(float4*)(&ws[kk][n4 * 4]) =
                *(const float4*)(wo + (size_t)(k0 + kk) * HH + n4 * 4);
        }
        __syncthreads();
#pragma unroll
        for (int kk = 0; kk < 16; ++kk) {
            const float xv = xs[row][kk];
#pragma unroll
            for (int q = 0; q < 4; ++q) {
                const float4 wv = *(const float4*)(&ws[kk][c16 * 4 + q * 128]);
                fma4(acc[q], xv, wv);
            }
        }
        __syncthreads();
    }

    const int grow = m0 + row;
    float4 v4[4];
    float sum = 0.0f, sq = 0.0f;
#pragma unroll
    for (int q = 0; q < 4; ++q) {
        const int col = c16 * 4 + q * 128;
        const float4 b4 = *(const float4*)(bo + col);
        const float4 r4 = *(const float4*)(x + (size_t)grow * HH + col);
        float4 tv;
        tv.x = acc[q].x + b4.x + r4.x;
        tv.y = acc[q].y + b4.y + r4.y;
        tv.z = acc[q].z + b4.z + r4.z;
        tv.w = acc[q].w + b4.w + r4.w;
        v4[q] = tv;
        sum += tv.x + tv.y + tv.z + tv.w;
        sq  += tv.x * tv.x + tv.y * tv.y + tv.z * tv.z + tv.w * tv.w;
    }
    // reduce across the 32 lanes sharing this row (lanes stay inside a wave half)
#pragma unroll
    for (int o = 1; o < 32; o <<= 1) {
        sum += __shfl_xor(sum, o, 64);
        sq  += __shfl_xor(sq, o, 64);
    }
    const float mu  = sum * (1.0f / 512.0f);
    const float var = sq * (1.0f / 512.0f) - mu * mu;
    const float rs  = rsqrtf(var + 1e-5f);
#pragma unroll
    for (int q = 0; q < 4; ++q) {
        const int col = c16 * 4 + q * 128;
        const float4 g4 = *(const float4*)(ln_g + col);
        const float4 be4 = *(const float4*)(ln_b + col);
        float4 o4;
        o4.x = (v4[q].x - mu) * rs * g4.x + be4.x;
        o4.y = (v4[q].y - mu) * rs * g4.y + be4.y;
        o4.z = (v4[q].z - mu) * rs * g4.z + be4.z;
        o4.w = (v4[q].w - mu) * rs * g4.w + be4.w;
        *(float4*)(out + (size_t)grow * HH + col) = o4;
    }
}

// ---------------------------------------------------------------------------
extern "C" void kernel_launch(void* const* d_in, const int* in_sizes, int n_in,
                              void* d_out, int out_size, void* d_ws, size_t ws_size,
                              hipStream_t stream)
{
    const float* x      = (const float*)d_in[0];
    const int*   mask   = (const int*)d_in[1];   // bool in ref; int32 on device (verified R1)
    const float* refCov = (const float*)d_in[2];
    const float* wq = (const float*)d_in[3];
    const float* bq = (const float*)d_in[4];
    const float* wk = (const float*)d_in[5];
    const float* bk = (const float*)d_in[6];
    const float* wv = (const float*)d_in[7];
    const float* bv = (const float*)d_in[8];
    const float* wo = (const float*)d_in[9];
    const float* bo = (const float*)d_in[10];
    const float* r1w = (const float*)d_in[11];
    const float* r1b = (const float*)d_in[12];
    const float* r2w = (const float*)d_in[13];
    const float* r2b = (const float*)d_in[14];
    const float* ln_g = (const float*)d_in[15];
    const float* ln_b = (const float*)d_in[16];
    float* out = (float*)d_out;

    // workspace layout (floats): q,k,v 1M each; ref 8M; attn-out 1M
    float* ws   = (float*)d_ws;
    float* qb   = ws;
    float* kb   = qb + 1048576;
    float* vb   = kb + 1048576;
    float* refc = vb + 1048576;
    float* aout = refc + 8388608;

    k_qkv     <<<dim3(32, 24), 256, 0, stream>>>(x, wq, bq, wk, bk, wv, bv, qb, kb, vb);
    k_refmlp  <<<4096,         256, 0, stream>>>(refCov, r1w, r1b, r2w, r2b, refc);
    k_attn_pv <<<dim3(32, 16), 256, 0, stream>>>(qb, kb, vb, mask, refc, aout);
    k_proj_ln <<<256,          256, 0, stream>>>(aout, wo, bo, x, ln_g, ln_b, out);
}

// Round 9
// 534.426 us; speedup vs baseline: 2.8400x; 2.8400x over previous
//
#include <hip/hip_runtime.h>
#include <math.h>

// Problem constants (B,L,H,NH fixed by reference)
#define BB 4
#define LL 512
#define HH 512
#define NHH 8
#define DKK 64
#define RIN 53

// R8 post-mortem (keep): fully-fused attn+PV spilled to scratch
// (WRITE_SIZE 2.07GB, VGPR=128, occ 23%, 1060us). Fusion line abandoned;
// split kernels + occupancy tuning instead.

__device__ inline void fma4(float4& a, float s, const float4& b) {
    a.x = fmaf(s, b.x, a.x); a.y = fmaf(s, b.y, a.y);
    a.z = fmaf(s, b.z, a.z); a.w = fmaf(s, b.w, a.w);
}

// ---------------------------------------------------------------------------
// Kernel 1: fused QKV projection.
// x[B*L, H] @ {wq|wk|wv}[H,H] + bias -> q/k/v stored [B,NH,L,DK].
// ---------------------------------------------------------------------------
__global__ __launch_bounds__(256) void k_qkv(
    const float* __restrict__ x,
    const float* __restrict__ wq, const float* __restrict__ bq,
    const float* __restrict__ wk, const float* __restrict__ bk,
    const float* __restrict__ wv, const float* __restrict__ bv,
    float* __restrict__ qb, float* __restrict__ kb, float* __restrict__ vb)
{
    __shared__ float As[64][20];   // 64 rows x 16 k (pad 20 to dodge bank conflicts)
    __shared__ float Bs[16][64];

    const int t  = threadIdx.x;
    const int bm = blockIdx.x;          // 0..31
    const int bn = blockIdx.y;          // 0..23
    const int mat = bn >> 3;            // 0:q 1:k 2:v
    const float* w    = (mat == 0) ? wq : (mat == 1) ? wk : wv;
    const float* bias = (mat == 0) ? bq : (mat == 1) ? bk : bv;
    float* dst        = (mat == 0) ? qb : (mat == 1) ? kb : vb;
    const int n0 = (bn & 7) * 64;       // col base within 512

    const int tx = t & 15, ty = t >> 4;
    float acc[4][4] = {};

    const int ar = t >> 2, ak4 = t & 3;     // A staging: row, k-quad
    const int wkk = t >> 4, wn4 = t & 15;   // B staging

    for (int k0 = 0; k0 < HH; k0 += 16) {
        *(float4*)(&As[ar][ak4 * 4]) =
            *(const float4*)(x + (bm * 64 + ar) * HH + k0 + ak4 * 4);
        *(float4*)(&Bs[wkk][wn4 * 4]) =
            *(const float4*)(w + (k0 + wkk) * HH + n0 + wn4 * 4);
        __syncthreads();
#pragma unroll
        for (int kk = 0; kk < 16; ++kk) {
            const float a0 = As[ty * 4 + 0][kk];
            const float a1 = As[ty * 4 + 1][kk];
            const float a2 = As[ty * 4 + 2][kk];
            const float a3 = As[ty * 4 + 3][kk];
            const float4 b4 = *(const float4*)(&Bs[kk][tx * 4]);
            acc[0][0] = fmaf(a0, b4.x, acc[0][0]); acc[0][1] = fmaf(a0, b4.y, acc[0][1]);
            acc[0][2] = fmaf(a0, b4.z, acc[0][2]); acc[0][3] = fmaf(a0, b4.w, acc[0][3]);
            acc[1][0] = fmaf(a1, b4.x, acc[1][0]); acc[1][1] = fmaf(a1, b4.y, acc[1][1]);
            acc[1][2] = fmaf(a1, b4.z, acc[1][2]); acc[1][3] = fmaf(a1, b4.w, acc[1][3]);
            acc[2][0] = fmaf(a2, b4.x, acc[2][0]); acc[2][1] = fmaf(a2, b4.y, acc[2][1]);
            acc[2][2] = fmaf(a2, b4.z, acc[2][2]); acc[2][3] = fmaf(a2, b4.w, acc[2][3]);
            acc[3][0] = fmaf(a3, b4.x, acc[3][0]); acc[3][1] = fmaf(a3, b4.y, acc[3][1]);
            acc[3][2] = fmaf(a3, b4.z, acc[3][2]); acc[3][3] = fmaf(a3, b4.w, acc[3][3]);
        }
        __syncthreads();
    }

    // epilogue: add bias, scatter into [B,NH,L,DK]
    const int ncol = n0 + tx * 4;           // within 512; 4 cols stay in one head
    const float4 b4 = *(const float4*)(bias + ncol);
    const int h = ncol >> 6, d0 = ncol & 63;
#pragma unroll
    for (int i = 0; i < 4; ++i) {
        const int grow = bm * 64 + ty * 4 + i;     // b*L + iseq
        const int b = grow >> 9, iseq = grow & 511;
        float4 r;
        r.x = acc[i][0] + b4.x; r.y = acc[i][1] + b4.y;
        r.z = acc[i][2] + b4.z; r.w = acc[i][3] + b4.w;
        *(float4*)(dst + ((size_t)(b * NHH + h) * LL + iseq) * DKK + d0) = r;
    }
}

// ---------------------------------------------------------------------------
// Kernel 2: ref-covariate MLP (R1 fix: LDS-staged rows; see journal).
// ---------------------------------------------------------------------------
__global__ __launch_bounds__(256) void k_refmlp(
    const float* __restrict__ refCov,
    const float* __restrict__ r1w, const float* __restrict__ r1b,
    const float* __restrict__ r2w, const float* __restrict__ r2b,
    float* __restrict__ ref)
{
    __shared__ float cov[256 * RIN];   // 13568 floats = 54272 B -> 3 blocks/CU

    const int t = threadIdx.x;
    const size_t base = (size_t)blockIdx.x * (256 * RIN);

    { // coalesced staging: 3392 float4s = 13 full passes + 64-thread tail
        const float4* src = (const float4*)(refCov + base);
        float4* dst = (float4*)cov;
#pragma unroll
        for (int p = 0; p < 13; ++p) dst[p * 256 + t] = src[p * 256 + t];
        if (t < 64) dst[13 * 256 + t] = src[13 * 256 + t];
    }
    __syncthreads();

    const int pi = blockIdx.x * 256 + t;            // (b*L+i)*L + j  (< 2^20)
    const int j  = pi & 511;
    const int bi = pi >> 9;                         // b*L + i
    const int b  = bi >> 9, i = bi & 511;
    const float* cw = cov + t * RIN;

    float hid[32];
#pragma unroll
    for (int h = 0; h < 32; ++h) hid[h] = r1b[h];

#pragma unroll 4
    for (int kk = 0; kk < RIN; ++kk) {
        const float c = cw[kk];
#pragma unroll
        for (int h = 0; h < 32; ++h)
            hid[h] = fmaf(c, r1w[kk * 32 + h], hid[h]);
    }

    float out[8];
#pragma unroll
    for (int o = 0; o < 8; ++o) out[o] = r2b[o];
#pragma unroll
    for (int h = 0; h < 32; ++h) {
        const float hv = fmaxf(hid[h], 0.0f);
#pragma unroll
        for (int o = 0; o < 8; ++o)
            out[o] = fmaf(hv, r2w[h * 8 + o], out[o]);
    }
#pragma unroll
    for (int o = 0; o < 8; ++o)
        ref[((size_t)(b * NHH + o) * LL + i) * LL + j] = out[o];
}

// ---------------------------------------------------------------------------
// Kernel 3a (R4 version, reverted): scores+softmax of qk, softmax of ref,
// comb = normalize(attn+ref) IN PLACE over ref buffer.
// ---------------------------------------------------------------------------
__global__ __launch_bounds__(256, 2) void k_attn_comb(
    const float* __restrict__ qb, const float* __restrict__ kb,
    const int* __restrict__ mask,
    float* refcomb)
{
    __shared__ float4 q4s[16][32];    // [d4][row]
    __shared__ float4 k4s[16][128];   // [d4][j_local]
    __shared__ float  mval[LL];

    const int t  = threadIdx.x;
    const int bh = blockIdx.x;        // b*NH + h
    const int b  = bh >> 3;
    const int i0 = blockIdx.y * 32;
    const int r  = t >> 3, c = t & 7;

    { // stage Q tile (32 rows x 64 d) and mask row
        const int d4 = t >> 4, r0 = t & 15;
#pragma unroll
        for (int p = 0; p < 2; ++p) {
            const int rr = r0 + p * 16;
            q4s[d4][rr] = *(const float4*)(qb + ((size_t)bh * LL + i0 + rr) * DKK + d4 * 4);
        }
#pragma unroll
        for (int p = 0; p < 2; ++p) {
            const int jj = t + p * 256;
            mval[jj] = (mask[b * LL + jj] != 0) ? 1.0f : 0.0f;
        }
    }

    float s0[16], s1[16], s2[16], s3[16];
    float rv0[16], rv1[16], rv2[16], rv3[16];

    auto compChunk = [&](float (&SS)[16], int CH) {
        { // stage K chunk: 128 j x 16 d4
            const int d4s = t >> 4, jb0 = t & 15;
#pragma unroll
            for (int p = 0; p < 8; ++p) {
                const int jl = jb0 + p * 16;
                k4s[d4s][jl] =
                    *(const float4*)(kb + ((size_t)bh * LL + CH * 128 + jl) * DKK + d4s * 4);
            }
        }
        __syncthreads();
#pragma unroll
        for (int mm = 0; mm < 16; ++mm) SS[mm] = 0.0f;
        for (int d4 = 0; d4 < 16; ++d4) {
            const float4 qv = q4s[d4][r];
#pragma unroll
            for (int mm = 0; mm < 16; ++mm) {
                const float4 kv = k4s[d4][c + 8 * mm];
                SS[mm] = fmaf(qv.x, kv.x, SS[mm]);
                SS[mm] = fmaf(qv.y, kv.y, SS[mm]);
                SS[mm] = fmaf(qv.z, kv.z, SS[mm]);
                SS[mm] = fmaf(qv.w, kv.w, SS[mm]);
            }
        }
        __syncthreads();
    };

    compChunk(s0, 0); compChunk(s1, 1); compChunk(s2, 2); compChunk(s3, 3);

    const bool rowv = mval[i0 + r] > 0.5f;
    float mx;   // running row max
    bool  uni;  // fully-masked row -> uniform softmax
    float dsum;

    auto maskScale = [&](float (&SS)[16], int CH, float scale) {
#pragma unroll
        for (int mm = 0; mm < 16; ++mm) {
            const int jj = c + 8 * (CH * 16 + mm);
            const bool val = rowv && (mval[jj] > 0.5f);
            SS[mm] = val ? SS[mm] * scale : -INFINITY;
            mx = fmaxf(mx, SS[mm]);
        }
    };
    auto expSum = [&](float (&SS)[16]) {
#pragma unroll
        for (int mm = 0; mm < 16; ++mm) {
            float pv;
            if (uni)                       pv = 1.0f;
            else if (SS[mm] == -INFINITY)  pv = 0.0f;
            else                           pv = __expf(SS[mm] - mx);
            SS[mm] = pv; dsum += pv;
        }
    };
    auto red8max = [&](float v) {
        for (int o = 1; o < 8; o <<= 1) v = fmaxf(v, __shfl_xor(v, o, 64));
        return v;
    };
    auto red8sum = [&](float v) {
        for (int o = 1; o < 8; o <<= 1) v += __shfl_xor(v, o, 64);
        return v;
    };

    // -------- attention softmax --------
    mx = -INFINITY;
    maskScale(s0, 0, 0.125f); maskScale(s1, 1, 0.125f);
    maskScale(s2, 2, 0.125f); maskScale(s3, 3, 0.125f);
    mx = red8max(mx);
    uni = (mx == -INFINITY);
    dsum = 0.0f;
    expSum(s0); expSum(s1); expSum(s2); expSum(s3);
    const float da = red8sum(dsum);

    // -------- ref softmax --------
    {
        const float* rrow = refcomb + ((size_t)bh * LL + i0 + r) * LL;
#pragma unroll
        for (int mm = 0; mm < 16; ++mm) {
            rv0[mm] = rrow[c + 8 * mm];
            rv1[mm] = rrow[c + 8 * (16 + mm)];
            rv2[mm] = rrow[c + 8 * (32 + mm)];
            rv3[mm] = rrow[c + 8 * (48 + mm)];
        }
    }
    mx = -INFINITY;
    maskScale(rv0, 0, 1.0f); maskScale(rv1, 1, 1.0f);
    maskScale(rv2, 2, 1.0f); maskScale(rv3, 3, 1.0f);
    mx = red8max(mx);
    uni = (mx == -INFINITY);
    dsum = 0.0f;
    expSum(rv0); expSum(rv1); expSum(rv2); expSum(rv3);
    const float dr = red8sum(dsum);

    // -------- combine, renormalize, store --------
    const float invda = 1.0f / da, invdr = 1.0f / dr;
    float tsum = 0.0f;
    auto combSum = [&](float (&SS)[16], float (&TT)[16]) {
#pragma unroll
        for (int mm = 0; mm < 16; ++mm) {
            const float cm = SS[mm] * invda + TT[mm] * invdr;
            SS[mm] = cm; tsum += cm;
        }
    };
    combSum(s0, rv0); combSum(s1, rv1); combSum(s2, rv2); combSum(s3, rv3);
    const float invt = 1.0f / red8sum(tsum);

    {
        float* orow = refcomb + ((size_t)bh * LL + i0 + r) * LL;
#pragma unroll
        for (int mm = 0; mm < 16; ++mm) {
            orow[c + 8 * mm]        = s0[mm] * invt;
            orow[c + 8 * (16 + mm)] = s1[mm] * invt;
            orow[c + 8 * (32 + mm)] = s2[mm] * invt;
            orow[c + 8 * (48 + mm)] = s3[mm] * invt;
        }
    }
}

// ---------------------------------------------------------------------------
// Kernel 3b: out = comb @ v per (b,h).
// R9 occupancy retile: R4 ran grid (32,8) = 256 blocks = 1 block/CU
// (4 waves of 32 -> latency-bound, Occupancy ~12%). Now i-tile 32 rows:
// grid (32,16) = 512 blocks, LDS 25KB -> 6 blocks/CU = 24 waves. Each
// thread: 2 rows (rg*2..+1) x 4 cols (dq*4..+3). Same math/order per output.
// ---------------------------------------------------------------------------
__global__ __launch_bounds__(256) void k_pv(
    const float* __restrict__ comb, const float* __restrict__ vb,
    float* __restrict__ aout)
{
    __shared__ float cs[32][68];   // comb tile [row][k], pad 68
    __shared__ float vs[64][64];   // v tile [k][d]

    const int t  = threadIdx.x;
    const int bh = blockIdx.x, b = bh >> 3, h = bh & 7;
    const int i0 = blockIdx.y * 32;
    const int dq = t & 15, rg = t >> 4;   // thread: rows rg*2..+1, cols dq*4..+3
    float4 acc[2] = {};

    for (int k0 = 0; k0 < LL; k0 += 64) {
#pragma unroll
        for (int p = 0; p < 2; ++p) {   // cs: 32 rows x 64 k = 512 float4
            const int flat = p * 256 + t;
            const int row = flat >> 4, k4 = flat & 15;
            *(float4*)(&cs[row][k4 * 4]) =
                *(const float4*)(comb + ((size_t)bh * LL + i0 + row) * LL + k0 + k4 * 4);
        }
#pragma unroll
        for (int p = 0; p < 4; ++p) {   // vs: 64 k x 64 d = 1024 float4
            const int flat = p * 256 + t;
            const int row = flat >> 4, k4 = flat & 15;
            *(float4*)(&vs[row][k4 * 4]) =
                *(const float4*)(vb + ((size_t)bh * LL + k0 + row) * DKK + k4 * 4);
        }
        __syncthreads();
#pragma unroll
        for (int kk4 = 0; kk4 < 16; ++kk4) {
            float4 vv[4];
#pragma unroll
            for (int q = 0; q < 4; ++q)
                vv[q] = *(const float4*)(&vs[kk4 * 4 + q][dq * 4]);
#pragma unroll
            for (int rr = 0; rr < 2; ++rr) {
                const float4 cv = *(const float4*)(&cs[rg * 2 + rr][kk4 * 4]);
                fma4(acc[rr], cv.x, vv[0]);
                fma4(acc[rr], cv.y, vv[1]);
                fma4(acc[rr], cv.z, vv[2]);
                fma4(acc[rr], cv.w, vv[3]);
            }
        }
        __syncthreads();
    }
#pragma unroll
    for (int rr = 0; rr < 2; ++rr) {
        const int i = i0 + rg * 2 + rr;
        *(float4*)(aout + ((size_t)(b * LL + i) * NHH + h) * DKK + dq * 4) = acc[rr];
    }
}

// ---------------------------------------------------------------------------
// Kernel 4: out-projection + bias + residual + LayerNorm, fused.
// R9 occupancy retile: R4 ran 256 blocks (8 rows each) = 1 block/CU.
// Now 4 rows/block, grid 512; each row = one full wave (row = t>>6),
// 64-lane shuffle stats; thread covers cols c*4 and c*4+256. LDS 33KB
// -> 4 blocks/CU = 16 waves. Same math/order per output.
// ---------------------------------------------------------------------------
__global__ __launch_bounds__(256) void k_proj_ln(
    const float* __restrict__ aout, const float* __restrict__ wo,
    const float* __restrict__ bo, const float* __restrict__ x,
    const float* __restrict__ ln_g, const float* __restrict__ ln_b,
    float* __restrict__ out)
{
    __shared__ float xs[4][20];
    __shared__ float ws[16][512];

    const int t   = threadIdx.x;
    const int m0  = blockIdx.x * 4;
    const int row = t >> 6;        // 0..3 (one wave per row)
    const int c   = t & 63;        // col = c*4 + q*256
    float4 acc[2] = {};

    for (int k0 = 0; k0 < HH; k0 += 16) {
        if (t < 16) {
            const int rr = t >> 2, k4 = t & 3;
            *(float4*)(&xs[rr][k4 * 4]) =
                *(const float4*)(aout + (size_t)(m0 + rr) * HH + k0 + k4 * 4);
        }
#pragma unroll
        for (int p = 0; p < 8; ++p) {
            const int flat = p * 256 + t;
            const int kk = flat >> 7, n4 = flat & 127;
            *(float4*)(&ws[kk][n4 * 4]) =
                *(const float4*)(wo + (size_t)(k0 + kk) * HH + n4 * 4);
        }
        __syncthreads();
#pragma unroll
        for (int kk = 0; kk < 16; ++kk) {
            const float xv = xs[row][kk];
#pragma unroll
            for (int q = 0; q < 2; ++q) {
                const float4 wv = *(const float4*)(&ws[kk][c * 4 + q * 256]);
                fma4(acc[q], xv, wv);
            }
        }
        __syncthreads();
    }

    const int grow = m0 + row;
    float4 v4[2];
    float sum = 0.0f, sq = 0.0f;
#pragma unroll
    for (int q = 0; q < 2; ++q) {
        const int col = c * 4 + q * 256;
        const float4 b4 = *(const float4*)(bo + col);
        const float4 r4 = *(const float4*)(x + (size_t)grow * HH + col);
        float4 tv;
        tv.x = acc[q].x + b4.x + r4.x;
        tv.y = acc[q].y + b4.y + r4.y;
        tv.z = acc[q].z + b4.z + r4.z;
        tv.w = acc[q].w + b4.w + r4.w;
        v4[q] = tv;
        sum += tv.x + tv.y + tv.z + tv.w;
        sq  += tv.x * tv.x + tv.y * tv.y + tv.z * tv.z + tv.w * tv.w;
    }
    // full-wave (64-lane) reduction: each row occupies exactly one wave
#pragma unroll
    for (int o = 1; o < 64; o <<= 1) {
        sum += __shfl_xor(sum, o, 64);
        sq  += __shfl_xor(sq, o, 64);
    }
    const float mu  = sum * (1.0f / 512.0f);
    const float var = sq * (1.0f / 512.0f) - mu * mu;
    const float rs  = rsqrtf(var + 1e-5f);
#pragma unroll
    for (int q = 0; q < 2; ++q) {
        const int col = c * 4 + q * 256;
        const float4 g4 = *(const float4*)(ln_g + col);
        const float4 be4 = *(const float4*)(ln_b + col);
        float4 o4;
        o4.x = (v4[q].x - mu) * rs * g4.x + be4.x;
        o4.y = (v4[q].y - mu) * rs * g4.y + be4.y;
        o4.z = (v4[q].z - mu) * rs * g4.z + be4.z;
        o4.w = (v4[q].w - mu) * rs * g4.w + be4.w;
        *(float4*)(out + (size_t)grow * HH + col) = o4;
    }
}

// ---------------------------------------------------------------------------
extern "C" void kernel_launch(void* const* d_in, const int* in_sizes, int n_in,
                              void* d_out, int out_size, void* d_ws, size_t ws_size,
                              hipStream_t stream)
{
    const float* x      = (const float*)d_in[0];
    const int*   mask   = (const int*)d_in[1];   // bool in ref; int32 on device (verified R1)
    const float* refCov = (const float*)d_in[2];
    const float* wq = (const float*)d_in[3];
    const float* bq = (const float*)d_in[4];
    const float* wk = (const float*)d_in[5];
    const float* bk = (const float*)d_in[6];
    const float* wv = (const float*)d_in[7];
    const float* bv = (const float*)d_in[8];
    const float* wo = (const float*)d_in[9];
    const float* bo = (const float*)d_in[10];
    const float* r1w = (const float*)d_in[11];
    const float* r1b = (const float*)d_in[12];
    const float* r2w = (const float*)d_in[13];
    const float* r2b = (const float*)d_in[14];
    const float* ln_g = (const float*)d_in[15];
    const float* ln_b = (const float*)d_in[16];
    float* out = (float*)d_out;

    // workspace layout (floats): q,k,v 1M each; ref/comb 8M; attn-out 1M
    float* ws   = (float*)d_ws;
    float* qb   = ws;
    float* kb   = qb + 1048576;
    float* vb   = kb + 1048576;
    float* refc = vb + 1048576;
    float* aout = refc + 8388608;

    k_qkv      <<<dim3(32, 24), 256, 0, stream>>>(x, wq, bq, wk, bk, wv, bv, qb, kb, vb);
    k_refmlp   <<<4096,         256, 0, stream>>>(refCov, r1w, r1b, r2w, r2b, refc);
    k_attn_comb<<<dim3(32, 16), 256, 0, stream>>>(qb, kb, mask, refc);
    k_pv       <<<dim3(32, 16), 256, 0, stream>>>(refc, vb, aout);
    k_proj_ln  <<<512,          256, 0, stream>>>(aout, wo, bo, x, ln_g, ln_b, out);
}